// Round 8
// baseline (301.496 us; speedup 1.0000x reference)
//
#include <hip/hip_runtime.h>

#define NTOK 16384
#define CCH  256
#define DH   128
#define KSPLIT 4

typedef float f32x4  __attribute__((ext_vector_type(4)));
typedef short bf16x8 __attribute__((ext_vector_type(8)));
typedef short bf16x4 __attribute__((ext_vector_type(4)));

__device__ __forceinline__ unsigned short f2bf(float f) {
    unsigned int u = __builtin_bit_cast(unsigned int, f);
    u += 0x7fffu + ((u >> 16) & 1u);   // round-to-nearest-even
    return (unsigned short)(u >> 16);
}
__device__ __forceinline__ float bf2f(unsigned short h) {
    unsigned int u = ((unsigned int)h) << 16;
    return __builtin_bit_cast(float, u);
}
// fast round-half-up bf16 (hot loop only; inputs positive finite)
__device__ __forceinline__ unsigned short f2bf_fast(float f) {
    unsigned int u = __builtin_bit_cast(unsigned int, f);
    return (unsigned short)((u + 0x8000u) >> 16);
}
// async global->LDS DMA, 16 B/lane. LDS dest = wave-uniform base + lane*16.
__device__ __forceinline__ void load_lds16(const unsigned short* g, unsigned short* l) {
    __builtin_amdgcn_global_load_lds(
        (const __attribute__((address_space(1))) unsigned int*)g,
        (__attribute__((address_space(3))) unsigned int*)l, 16, 0, 0);
}

// ---------------------------------------------------------------------------
// Kernel 1 (fused): q/k/v = W @ x (+bias), bf16. Q,K [N][128]; V [128][N].
// Q folds in (1/16)*log2(e). grid 512: 32-token tiles; x tile staged ONCE,
// per-K-chunk all three W tiles staged, B-frag shared across q/k/v.
// ---------------------------------------------------------------------------
__global__ __launch_bounds__(256) void qkv_fused(
    const float* __restrict__ x,
    const float* __restrict__ Wq, const float* __restrict__ bq,
    const float* __restrict__ Wk, const float* __restrict__ bk,
    const float* __restrict__ Wv, const float* __restrict__ bv,
    unsigned short* __restrict__ Qb, unsigned short* __restrict__ Kb,
    unsigned short* __restrict__ Vb)
{
    __shared__ unsigned short lX[32 * 264];       // [n 32][c 256 + pad 8]
    __shared__ unsigned short lW[3 * DH * 40];    // [which][o 128][c 32 + pad]

    const int t    = threadIdx.x;
    const int wave = t >> 6, lane = t & 63, l16 = lane & 15, quad = lane >> 4;
    const int nt   = blockIdx.x;                  // 32-token tile

#pragma unroll
    for (int pass = 0; pass < 8; ++pass) {
        int c  = pass * 32 + (t >> 3);
        int n4 = t & 7;
        float4 xv = *(const float4*)(x + c * NTOK + nt * 32 + n4 * 4);
        lX[(n4 * 4 + 0) * 264 + c] = f2bf(xv.x);
        lX[(n4 * 4 + 1) * 264 + c] = f2bf(xv.y);
        lX[(n4 * 4 + 2) * 264 + c] = f2bf(xv.z);
        lX[(n4 * 4 + 3) * 264 + c] = f2bf(xv.w);
    }

    f32x4 acc[3][2][2];
#pragma unroll
    for (int wch = 0; wch < 3; ++wch)
#pragma unroll
        for (int os = 0; os < 2; ++os)
#pragma unroll
            for (int ns = 0; ns < 2; ++ns) acc[wch][os][ns] = (f32x4){0, 0, 0, 0};

    for (int kc8 = 0; kc8 < 8; ++kc8) {
        __syncthreads();
#pragma unroll
        for (int wch = 0; wch < 3; ++wch) {
            const float* W = (wch == 0) ? Wq : ((wch == 1) ? Wk : Wv);
#pragma unroll
            for (int p = 0; p < 4; ++p) {
                int idx = p * 256 + t;
                int row = idx >> 3, col4 = idx & 7;
                float4 wv = *(const float4*)(W + row * CCH + kc8 * 32 + col4 * 4);
                bf16x4 pk = { (short)f2bf(wv.x), (short)f2bf(wv.y),
                              (short)f2bf(wv.z), (short)f2bf(wv.w) };
                *(bf16x4*)(&lW[wch * DH * 40 + row * 40 + col4 * 4]) = pk;
            }
        }
        __syncthreads();

        bf16x8 bfr[2];
#pragma unroll
        for (int ns = 0; ns < 2; ++ns)
            bfr[ns] = *(const bf16x8*)(&lX[(ns * 16 + l16) * 264 + kc8 * 32 + quad * 8]);
#pragma unroll
        for (int wch = 0; wch < 3; ++wch)
#pragma unroll
            for (int os = 0; os < 2; ++os) {
                bf16x8 afr = *(const bf16x8*)(&lW[wch * DH * 40 + (wave * 32 + os * 16 + l16) * 40 + quad * 8]);
                acc[wch][os][0] = __builtin_amdgcn_mfma_f32_16x16x32_bf16(afr, bfr[0], acc[wch][os][0], 0, 0, 0);
                acc[wch][os][1] = __builtin_amdgcn_mfma_f32_16x16x32_bf16(afr, bfr[1], acc[wch][os][1], 0, 0, 0);
            }
    }

#pragma unroll
    for (int wch = 0; wch < 3; ++wch) {
        const float* bias = (wch == 0) ? bq : ((wch == 1) ? bk : bv);
        const float oscale = (wch == 0) ? 0.0625f * 1.44269504f : 1.0f;
#pragma unroll
        for (int os = 0; os < 2; ++os)
#pragma unroll
            for (int ns = 0; ns < 2; ++ns)
#pragma unroll
                for (int r = 0; r < 4; ++r) {
                    int o = wave * 32 + os * 16 + quad * 4 + r;
                    int n = nt * 32 + ns * 16 + l16;
                    float v = (acc[wch][os][ns][r] + bias[o]) * oscale;
                    if (wch == 2)       Vb[o * NTOK + n] = f2bf(v);
                    else if (wch == 0)  Qb[n * DH + o]   = f2bf(v);
                    else                Kb[n * DH + o]   = f2bf(v);
                }
    }
}

// ---------------------------------------------------------------------------
// Kernel 2: split-K flash attention, static max (m=0), 64 Q-rows per wave.
// grid (64, KSPLIT), 256 threads, 1 block/CU. Block (qb,s): Q rows
// [qb*256,+256), 64 key tiles of 64. Double-buffered K/V LDS: DMA for tile
// i+1 issued right after the single per-iter barrier, drained a full
// iteration later (no exposed vmcnt(0) stall). XOR swizzle on the global
// gather side keeps staging AND frag reads conflict-free.
// S computed transposed (S^T = K Q^T): lane col = qrow, rows = 4 consecutive
// keys -> packed b64 P writes; l is per-lane scalar, reduced in epilogue.
// Writes l-normalized partial O (bf16, [N][128]) + l (fp32).
// Dynamic LDS layout (shorts): lK[2][8192] | lV[2][8192] | lP[4][64*LPS]
// ---------------------------------------------------------------------------
#define LPS 72

__global__ __launch_bounds__(256, 1) void flash_attn(
    const unsigned short* __restrict__ Qb, const unsigned short* __restrict__ Kb,
    const unsigned short* __restrict__ Vb,
    unsigned short* __restrict__ P0, unsigned short* __restrict__ P123,
    float* __restrict__ lbuf)
{
    extern __shared__ unsigned short smem[];
    unsigned short* lKb = smem;                 // 2 * 8192
    unsigned short* lVb = smem + 16384;         // 2 * 8192
    unsigned short* lPb = smem + 32768;         // 4 * 64 * LPS

    const int t    = threadIdx.x;
    const int wave = t >> 6, lane = t & 63, l16 = lane & 15, quad = lane >> 4;
    const int qrow0 = blockIdx.x * 256 + wave * 64;
    const int split = blockIdx.y;
    const int tile0 = split * 64;                 // 64 tiles per split

    // Q B-frags for the 4 16-row sets (resident all kernel)
    bf16x8 qa[4][4];
#pragma unroll
    for (int h = 0; h < 4; ++h)
#pragma unroll
        for (int kc = 0; kc < 4; ++kc)
            qa[h][kc] = *(const bf16x8*)(Qb + (qrow0 + h * 16 + l16) * DH + kc * 32 + quad * 8);

    f32x4 acc[4][8];
#pragma unroll
    for (int h = 0; h < 4; ++h)
#pragma unroll
        for (int i = 0; i < 8; ++i) acc[h][i] = (f32x4){0, 0, 0, 0};
    float lpart[4] = {0.f, 0.f, 0.f, 0.f};

    // prologue: DMA tile0 -> buffer 0
    {
        const unsigned short* Kt = Kb + (size_t)tile0 * 64 * DH;
        const int vcol = tile0 * 64;
#pragma unroll
        for (int p = 0; p < 4; ++p) {
            int s = p * 256 + t;
            int key = s >> 4, c16 = s & 15;
            load_lds16(Kt + key * DH + ((c16 ^ (key & 15)) << 3),
                       lKb + (p * 256 + wave * 64) * 8);
            int vr = s >> 3, vc = s & 7;
            load_lds16(Vb + vr * NTOK + vcol + ((vc ^ (vr & 7)) << 3),
                       lVb + (p * 256 + wave * 64) * 8);
        }
    }

    for (int it = 0; it < 64; ++it) {
        __syncthreads();   // drains last iter's DMA (a full iter old) + guards buffers

        // issue DMA for tile it+1 into the other buffer (overlaps compute).
        // Last iter prefetches tile0+64: for split 3 that reads the start of
        // Vb (allocated, never used).
        {
            const unsigned short* Kt = Kb + (size_t)(tile0 + it + 1) * 64 * DH;
            const int vcol = (tile0 + it + 1) * 64;
            unsigned short* dK = lKb + ((it + 1) & 1) * 8192;
            unsigned short* dV = lVb + ((it + 1) & 1) * 8192;
#pragma unroll
            for (int p = 0; p < 4; ++p) {
                int s = p * 256 + t;
                int key = s >> 4, c16 = s & 15;
                load_lds16(Kt + key * DH + ((c16 ^ (key & 15)) << 3),
                           dK + (p * 256 + wave * 64) * 8);
                int vr = s >> 3, vc = s & 7;
                load_lds16(Vb + vr * NTOK + vcol + ((vc ^ (vr & 7)) << 3),
                           dV + (p * 256 + wave * 64) * 8);
            }
        }

        const unsigned short* lK = lKb + (it & 1) * 8192;
        const unsigned short* lV = lVb + (it & 1) * 8192;

        // S^T = K Q^T for the 4 row sets; kb frag shared across h
        f32x4 sf[4][4];
#pragma unroll
        for (int h = 0; h < 4; ++h)
#pragma unroll
            for (int ns = 0; ns < 4; ++ns) sf[h][ns] = (f32x4){0, 0, 0, 0};
#pragma unroll
        for (int kc = 0; kc < 4; ++kc) {
#pragma unroll
            for (int ns = 0; ns < 4; ++ns) {
                bf16x8 kb = *(const bf16x8*)(&lK[(ns * 16 + l16) * DH + (((kc * 4 + quad) ^ l16) << 3)]);
#pragma unroll
                for (int h = 0; h < 4; ++h)
                    sf[h][ns] = __builtin_amdgcn_mfma_f32_16x16x32_bf16(kb, qa[h][kc], sf[h][ns], 0, 0, 0);
            }
        }

        // p = 2^s; per-lane l; P^T -> per-wave LDS as packed b64
        unsigned short* pb = &lPb[wave * 64 * LPS];
#pragma unroll
        for (int h = 0; h < 4; ++h)
#pragma unroll
            for (int ns = 0; ns < 4; ++ns) {
                float p0 = __builtin_amdgcn_exp2f(sf[h][ns][0]);
                float p1 = __builtin_amdgcn_exp2f(sf[h][ns][1]);
                float p2 = __builtin_amdgcn_exp2f(sf[h][ns][2]);
                float p3 = __builtin_amdgcn_exp2f(sf[h][ns][3]);
                lpart[h] += (p0 + p1) + (p2 + p3);
                bf16x4 pk = { (short)f2bf_fast(p0), (short)f2bf_fast(p1),
                              (short)f2bf_fast(p2), (short)f2bf_fast(p3) };
                *(bf16x4*)(pb + (h * 16 + l16) * LPS + ns * 16 + quad * 4) = pk;
            }

        bf16x8 pa[4][2];
#pragma unroll
        for (int h = 0; h < 4; ++h)
#pragma unroll
            for (int half = 0; half < 2; ++half)
                pa[h][half] = *(const bf16x8*)(pb + (h * 16 + l16) * LPS + half * 32 + quad * 8);

#pragma unroll
        for (int ds = 0; ds < 8; ++ds) {
            bf16x8 vb0 = *(const bf16x8*)(&lV[(ds * 16 + l16) * 64 + ((quad ^ (l16 & 7)) << 3)]);
            bf16x8 vb1 = *(const bf16x8*)(&lV[(ds * 16 + l16) * 64 + (((4 + quad) ^ (l16 & 7)) << 3)]);
#pragma unroll
            for (int h = 0; h < 4; ++h) {
                acc[h][ds] = __builtin_amdgcn_mfma_f32_16x16x32_bf16(pa[h][0], vb0, acc[h][ds], 0, 0, 0);
                acc[h][ds] = __builtin_amdgcn_mfma_f32_16x16x32_bf16(pa[h][1], vb1, acc[h][ds], 0, 0, 0);
            }
        }
    }

    // epilogue: reduce l across quads, broadcast, normalize, store
    float lsum[4];
#pragma unroll
    for (int h = 0; h < 4; ++h) {
        float s = lpart[h];
        s += __shfl_xor(s, 16);
        s += __shfl_xor(s, 32);
        lsum[h] = s;                 // every lane: l for qrow = h*16 + l16
    }

    unsigned short* base = (split == 0) ? P0 : (P123 + (size_t)(split - 1) * NTOK * DH);
#pragma unroll
    for (int h = 0; h < 4; ++h) {
        float inv[4];
#pragma unroll
        for (int r = 0; r < 4; ++r)
            inv[r] = 1.0f / __shfl(lsum[h], quad * 4 + r, 16);
#pragma unroll
        for (int ds = 0; ds < 8; ++ds)
#pragma unroll
            for (int r = 0; r < 4; ++r) {
                int row = qrow0 + h * 16 + quad * 4 + r;
                base[row * DH + ds * 16 + l16] = f2bf(acc[h][ds][r] * inv[r]);
            }
        if (quad == 0)
            lbuf[split * NTOK + qrow0 + h * 16 + l16] = lsum[h];
    }
}

// ---------------------------------------------------------------------------
// Kernel 2b: combine KSPLIT partials -> Ob bf16 [N][128]. In-place over the
// split-0 partial; consumes d_out scratch BEFORE out_proj writes d_out.
// ---------------------------------------------------------------------------
__global__ __launch_bounds__(256) void combine(
    const unsigned short* __restrict__ P123, const float* __restrict__ lbuf,
    unsigned short* __restrict__ Ob)
{
    const int t = threadIdx.x;
    const int n  = blockIdx.x * 32 + (t >> 3);
    const int sg = t & 7;

    const unsigned short* Pp[KSPLIT];
    Pp[0] = Ob;
#pragma unroll
    for (int s = 1; s < KSPLIT; ++s) Pp[s] = P123 + (size_t)(s - 1) * NTOK * DH;

    float w[KSPLIT], den = 0.f;
#pragma unroll
    for (int s = 0; s < KSPLIT; ++s) { w[s] = lbuf[s * NTOK + n]; den += w[s]; }
    float invden = 1.0f / den;
#pragma unroll
    for (int s = 0; s < KSPLIT; ++s) w[s] *= invden;

#pragma unroll
    for (int j = 0; j < 2; ++j) {
        bf16x8 v[KSPLIT];
#pragma unroll
        for (int s = 0; s < KSPLIT; ++s)
            v[s] = *(const bf16x8*)(Pp[s] + n * DH + sg * 16 + j * 8);
        bf16x8 o;
#pragma unroll
        for (int e = 0; e < 8; ++e) {
            float a = 0.f;
#pragma unroll
            for (int s = 0; s < KSPLIT; ++s)
                a += w[s] * bf2f((unsigned short)v[s][e]);
            o[e] = (short)f2bf(a);
        }
        *(bf16x8*)(Ob + n * DH + sg * 16 + j * 8) = o;
    }
}

// ---------------------------------------------------------------------------
// Kernel 3: out = Wo @ O^T + bo + x (residual), fp32. Coalesced epilogue via
// padded LDS tile. grid 512: blockIdx.x&1 = c-half, blockIdx.x>>1 = n-tile.
// ---------------------------------------------------------------------------
__global__ __launch_bounds__(256) void out_proj(
    const float* __restrict__ Wo, const float* __restrict__ bo,
    const float* __restrict__ x, const unsigned short* __restrict__ Ob,
    float* __restrict__ out)
{
    __shared__ unsigned short lW[DH * 72];   // [c 128][o 128 + pad 8]
    __shared__ float lsO[DH * 68];           // [c 128][n 64 + pad 4]

    const int t    = threadIdx.x;
    const int wave = t >> 6, lane = t & 63, l16 = lane & 15, quad = lane >> 4;
    const int ch = blockIdx.x & 1;
    const int n0 = (blockIdx.x >> 1) * 64;
    const int c0 = ch * 128;

#pragma unroll
    for (int i = 0; i < 16; ++i) {
        int idx = i * 256 + t;
        int row = idx >> 5, col4 = idx & 31;
        float4 wv = *(const float4*)(Wo + (c0 + row) * DH + col4 * 4);
        bf16x4 pk = { (short)f2bf(wv.x), (short)f2bf(wv.y),
                      (short)f2bf(wv.z), (short)f2bf(wv.w) };
        *(bf16x4*)(&lW[row * 72 + col4 * 4]) = pk;
    }
    __syncthreads();

    f32x4 acc[8];
#pragma unroll
    for (int i = 0; i < 8; ++i) acc[i] = (f32x4){0, 0, 0, 0};

#pragma unroll
    for (int kc = 0; kc < 4; ++kc) {
        bf16x8 bfr = *(const bf16x8*)(Ob + (n0 + wave * 16 + l16) * DH + kc * 32 + quad * 8);
#pragma unroll
        for (int cs = 0; cs < 8; ++cs) {
            bf16x8 afr = *(const bf16x8*)(&lW[(cs * 16 + l16) * 72 + kc * 32 + quad * 8]);
            acc[cs] = __builtin_amdgcn_mfma_f32_16x16x32_bf16(afr, bfr, acc[cs], 0, 0, 0);
        }
    }

#pragma unroll
    for (int cs = 0; cs < 8; ++cs)
#pragma unroll
        for (int r = 0; r < 4; ++r)
            lsO[(cs * 16 + quad * 4 + r) * 68 + wave * 16 + l16] = acc[cs][r];
    __syncthreads();

#pragma unroll
    for (int it = 0; it < 8; ++it) {
        int idx = it * 256 + t;
        int c  = idx >> 4;
        int n4 = idx & 15;
        float4 v = *(const float4*)(&lsO[c * 68 + n4 * 4]);
        float4 xv = *(const float4*)(x + (size_t)(c0 + c) * NTOK + n0 + n4 * 4);
        float b = bo[c0 + c];
        float4 o = { v.x + b + xv.x, v.y + b + xv.y, v.z + b + xv.z, v.w + b + xv.w };
        *(float4*)(out + (size_t)(c0 + c) * NTOK + n0 + n4 * 4) = o;
    }
}

// ---------------------------------------------------------------------------
extern "C" void kernel_launch(void* const* d_in, const int* in_sizes, int n_in,
                              void* d_out, int out_size, void* d_ws, size_t ws_size,
                              hipStream_t stream) {
    const float* x  = (const float*)d_in[0];
    const float* Wq = (const float*)d_in[1];
    const float* bq = (const float*)d_in[2];
    const float* Wk = (const float*)d_in[3];
    const float* bk = (const float*)d_in[4];
    const float* Wv = (const float*)d_in[5];
    const float* bv = (const float*)d_in[6];
    const float* Wo = (const float*)d_in[7];
    const float* bo = (const float*)d_in[8];
    float* out = (float*)d_out;

    char* w = (char*)d_ws;
    unsigned short* Qb = (unsigned short*)(w);                  // 4 MB  [N][128] bf16
    unsigned short* Kb = (unsigned short*)(w + (4u << 20));     // 4 MB  [N][128] bf16
    unsigned short* Vb = (unsigned short*)(w + (8u << 20));     // 4 MB  [128][N] bf16
    unsigned short* Ob = (unsigned short*)(w + (12u << 20));    // 4 MB: split-0 partial, then combined O
    // d_out doubles as scratch: splits 1..3 partial O (12 MB) + l array (256 KB).
    // combine consumes it fully before out_proj starts writing d_out.
    unsigned short* P123 = (unsigned short*)d_out;
    float*          lbuf = (float*)((char*)d_out + (12u << 20));

    qkv_fused<<<512, 256, 0, stream>>>(x, Wq, bq, Wk, bk, Wv, bv, Qb, Kb, Vb);
    flash_attn<<<dim3(64, KSPLIT), 256, 102400, stream>>>(Qb, Kb, Vb, Ob, P123, lbuf);
    combine<<<512, 256, 0, stream>>>(P123, lbuf, Ob);
    out_proj<<<512, 256, 0, stream>>>(Wo, bo, x, Ob, out);
}